// Round 1
// baseline (4390.466 us; speedup 1.0000x reference)
//
#include <hip/hip_runtime.h>
#include <hip/hip_bf16.h>

// PointCraft++: 6 transformer blocks (local MHA within 64-token parts +
// cross MHA to 49 image tokens) over a (64, 512, 256) state stream.
// Round 1: correct fp32 baseline. Generic tiled GEMM + fused attention +
// fused residual-LN. bf16 MFMA conversion planned for later rounds.

#define B_     64
#define P_     8
#define T_     64
#define S_     512          // P_*T_
#define D_     256
#define H_     8
#define DH_    32
#define NIMG_  49
#define M_ST   32768        // B_*S_
#define M_IMG  3136         // B_*NIMG_

// ---------------------------------------------------------------------------
// Generic GEMM: C[M,N] = A[M,K] @ W[N,K]^T + bias[N]
// BM=BN=64, BK=16, 256 threads, 4x4 micro-tile per thread.
// M must be a multiple of 64; N,K arbitrary (K multiple of 16).
// ---------------------------------------------------------------------------
__global__ __launch_bounds__(256) void gemm_bias(
    const float* __restrict__ A, const float* __restrict__ W,
    const float* __restrict__ bias, float* __restrict__ C,
    int M, int N, int K)
{
    __shared__ float As[64][17];
    __shared__ float Ws[64][17];
    const int tid = threadIdx.x;
    const int tx = tid & 15, ty = tid >> 4;
    const int row0 = blockIdx.x * 64, col0 = blockIdx.y * 64;

    float acc[4][4] = {};

    for (int k0 = 0; k0 < K; k0 += 16) {
        {   // A tile: 64x16, one float4 per thread
            int r = tid >> 2, c = (tid & 3) << 2;
            float4 v = *reinterpret_cast<const float4*>(
                A + (size_t)(row0 + r) * K + k0 + c);
            As[r][c+0] = v.x; As[r][c+1] = v.y; As[r][c+2] = v.z; As[r][c+3] = v.w;
        }
        {   // W tile: 64x16 (rows are output features), guarded for N<64 tiles
            int r = tid >> 2, c = (tid & 3) << 2;
            int n = col0 + r;
            float4 v = make_float4(0.f, 0.f, 0.f, 0.f);
            if (n < N)
                v = *reinterpret_cast<const float4*>(W + (size_t)n * K + k0 + c);
            Ws[r][c+0] = v.x; Ws[r][c+1] = v.y; Ws[r][c+2] = v.z; Ws[r][c+3] = v.w;
        }
        __syncthreads();
        #pragma unroll
        for (int k = 0; k < 16; ++k) {
            float a[4], b[4];
            #pragma unroll
            for (int i = 0; i < 4; ++i) a[i] = As[ty*4+i][k];
            #pragma unroll
            for (int j = 0; j < 4; ++j) b[j] = Ws[tx*4+j][k];
            #pragma unroll
            for (int i = 0; i < 4; ++i)
                #pragma unroll
                for (int j = 0; j < 4; ++j)
                    acc[i][j] += a[i] * b[j];
        }
        __syncthreads();
    }

    #pragma unroll
    for (int i = 0; i < 4; ++i) {
        size_t rbase = (size_t)(row0 + ty*4 + i) * N;
        #pragma unroll
        for (int j = 0; j < 4; ++j) {
            int n = col0 + tx*4 + j;
            if (n < N) C[rbase + n] = acc[i][j] + bias[n];
        }
    }
}

// ---------------------------------------------------------------------------
// st init: st[b, s, d] = init_part_tokens[s, d] + part_id_emb[s>>6, d]
// ---------------------------------------------------------------------------
__global__ __launch_bounds__(256) void init_st(
    float* __restrict__ st, const float* __restrict__ init_tokens,
    const float* __restrict__ pid_emb)
{
    size_t i = (size_t)blockIdx.x * 256 + threadIdx.x;   // over B_*S_*D_
    int d = i & 255;
    int s = (i >> 8) & 511;
    int p = s >> 6;
    st[i] = init_tokens[s * 256 + d] + pid_emb[p * 256 + d];
}

// ---------------------------------------------------------------------------
// Local attention: one block per (part, head). Sq=Sk=64, dh=32.
// qkv layout: [32768, 768] with q|k|v in 256-col chunks.
// out: [32768, 256], head h at cols h*32..h*32+31.
// ---------------------------------------------------------------------------
__global__ __launch_bounds__(256) void local_attn(
    const float* __restrict__ qkv, float* __restrict__ out)
{
    const int blk = blockIdx.x;          // 512*8
    const int bp  = blk >> 3, h = blk & 7;
    const int tid = threadIdx.x;

    __shared__ float qs[64][33], ks[64][33], vs[64][33];
    __shared__ float ps[64][65];

    const size_t base = (size_t)bp * 64 * 768;
    for (int idx = tid; idx < 2048; idx += 256) {
        int t = idx >> 5, d = idx & 31;
        size_t r = base + (size_t)t * 768 + h * 32 + d;
        qs[t][d] = qkv[r];
        ks[t][d] = qkv[r + 256];
        vs[t][d] = qkv[r + 512];
    }
    __syncthreads();

    const int row = tid >> 2, sub = tid & 3;

    float sc[16];
    #pragma unroll
    for (int j = 0; j < 16; ++j) {
        int c = sub * 16 + j;
        float acc = 0.f;
        #pragma unroll
        for (int k = 0; k < 32; ++k) acc += qs[row][k] * ks[c][k];
        sc[j] = acc * 0.17677669529663689f;   // 1/sqrt(32)
    }
    float m = sc[0];
    #pragma unroll
    for (int j = 1; j < 16; ++j) m = fmaxf(m, sc[j]);
    m = fmaxf(m, __shfl_xor(m, 1));
    m = fmaxf(m, __shfl_xor(m, 2));
    float sum = 0.f;
    #pragma unroll
    for (int j = 0; j < 16; ++j) { sc[j] = __expf(sc[j] - m); sum += sc[j]; }
    sum += __shfl_xor(sum, 1);
    sum += __shfl_xor(sum, 2);
    float inv = 1.f / sum;
    #pragma unroll
    for (int j = 0; j < 16; ++j) ps[row][sub * 16 + j] = sc[j] * inv;
    __syncthreads();

    float acc[8] = {};
    for (int k = 0; k < 64; ++k) {
        float p = ps[row][k];
        #pragma unroll
        for (int j = 0; j < 8; ++j) acc[j] += p * vs[k][sub * 8 + j];
    }
    size_t obase = ((size_t)bp * 64 + row) * 256 + h * 32 + sub * 8;
    #pragma unroll
    for (int j = 0; j < 8; ++j) out[obase + j] = acc[j];
}

// ---------------------------------------------------------------------------
// Cross attention: one block per (batch, head, q-chunk of 64). Sk=49.
// qp: [32768,256] (row = b*512+s), k_img/v_img: [3136,256] (row = b*49+n).
// ---------------------------------------------------------------------------
__global__ __launch_bounds__(256) void cross_attn(
    const float* __restrict__ qp, const float* __restrict__ kimg,
    const float* __restrict__ vimg, float* __restrict__ out)
{
    const int blk = blockIdx.x;          // 64*8*8
    const int b = blk >> 6, h = (blk >> 3) & 7, qc = blk & 7;
    const int tid = threadIdx.x;

    __shared__ float qs[64][33], ks[49][33], vs[49][33];
    __shared__ float ps[64][52];

    const size_t qbase = ((size_t)b * 512 + qc * 64) * 256 + h * 32;
    for (int idx = tid; idx < 2048; idx += 256) {
        int t = idx >> 5, d = idx & 31;
        qs[t][d] = qp[qbase + (size_t)t * 256 + d];
    }
    const size_t ibase = (size_t)b * 49 * 256 + h * 32;
    for (int idx = tid; idx < 1568; idx += 256) {
        int n = idx >> 5, d = idx & 31;
        ks[n][d] = kimg[ibase + (size_t)n * 256 + d];
        vs[n][d] = vimg[ibase + (size_t)n * 256 + d];
    }
    __syncthreads();

    const int row = tid >> 2, sub = tid & 3;

    float sc[13];
    int cnt = 0;
    float m = -1e30f;
    for (int c = sub; c < 49; c += 4) {
        float acc = 0.f;
        #pragma unroll
        for (int k = 0; k < 32; ++k) acc += qs[row][k] * ks[c][k];
        acc *= 0.17677669529663689f;
        sc[cnt++] = acc;
        m = fmaxf(m, acc);
    }
    m = fmaxf(m, __shfl_xor(m, 1));
    m = fmaxf(m, __shfl_xor(m, 2));
    float sum = 0.f;
    cnt = 0;
    for (int c = sub; c < 49; c += 4) {
        float e = __expf(sc[cnt] - m);
        sc[cnt++] = e;
        sum += e;
    }
    sum += __shfl_xor(sum, 1);
    sum += __shfl_xor(sum, 2);
    float inv = 1.f / sum;
    cnt = 0;
    for (int c = sub; c < 49; c += 4) ps[row][c] = sc[cnt++] * inv;
    __syncthreads();

    float acc[8] = {};
    for (int k = 0; k < 49; ++k) {
        float p = ps[row][k];
        #pragma unroll
        for (int j = 0; j < 8; ++j) acc[j] += p * vs[k][sub * 8 + j];
    }
    size_t obase = ((size_t)b * 512 + qc * 64 + row) * 256 + h * 32 + sub * 8;
    #pragma unroll
    for (int j = 0; j < 8; ++j) out[obase + j] = acc[j];
}

// ---------------------------------------------------------------------------
// Fused residual + LayerNorm: st = LN(st + delta) * w + b. One block per row.
// ---------------------------------------------------------------------------
__global__ __launch_bounds__(256) void ln_residual(
    float* __restrict__ st, const float* __restrict__ delta,
    const float* __restrict__ w, const float* __restrict__ b)
{
    const int row = blockIdx.x;
    const int tid = threadIdx.x;
    const size_t idx = (size_t)row * 256 + tid;

    float x = st[idx] + delta[idx];
    float s = x, s2 = x * x;
    #pragma unroll
    for (int o = 32; o; o >>= 1) {
        s  += __shfl_down(s, o);
        s2 += __shfl_down(s2, o);
    }
    __shared__ float red[8];
    int wave = tid >> 6, lane = tid & 63;
    if (lane == 0) { red[wave] = s; red[4 + wave] = s2; }
    __syncthreads();
    if (tid == 0) {
        float ts  = red[0] + red[1] + red[2] + red[3];
        float ts2 = red[4] + red[5] + red[6] + red[7];
        float mean = ts * (1.f / 256.f);
        float var  = ts2 * (1.f / 256.f) - mean * mean;
        red[0] = mean;
        red[1] = rsqrtf(var + 1e-5f);
    }
    __syncthreads();
    float mean = red[0], rs = red[1];
    st[idx] = (x - mean) * rs * w[tid] + b[tid];
}

// ---------------------------------------------------------------------------
extern "C" void kernel_launch(void* const* d_in, const int* in_sizes, int n_in,
                              void* d_out, int out_size, void* d_ws, size_t ws_size,
                              hipStream_t stream)
{
    const float* feat             = (const float*)d_in[0];
    const float* img_proj_w      = (const float*)d_in[1];
    const float* img_proj_b      = (const float*)d_in[2];
    const float* init_part_tokens = (const float*)d_in[3];
    const float* part_id_emb     = (const float*)d_in[4];
    const float* local_in_w      = (const float*)d_in[5];
    const float* local_in_b      = (const float*)d_in[6];
    const float* local_out_w     = (const float*)d_in[7];
    const float* local_out_b     = (const float*)d_in[8];
    const float* cross_in_w      = (const float*)d_in[9];
    const float* cross_in_b      = (const float*)d_in[10];
    const float* cross_out_w     = (const float*)d_in[11];
    const float* cross_out_b     = (const float*)d_in[12];
    const float* norm1_w         = (const float*)d_in[13];
    const float* norm1_b         = (const float*)d_in[14];
    const float* norm2_w         = (const float*)d_in[15];
    const float* norm2_b         = (const float*)d_in[16];
    const float* coord_w         = (const float*)d_in[17];
    const float* coord_b         = (const float*)d_in[18];
    float* out = (float*)d_out;

    // Workspace layout (fp32):
    //   st   : 32768*256   = 33.6 MB   (persistent state)
    //   big  : 32768*768   = 100.7 MB  (qkv, reused for proj / qp)
    //   attn : 32768*256   = 33.6 MB   (attention output)
    //   img/kimg/vimg : 3 * 3136*256 = 9.6 MB
    float* st   = (float*)d_ws;
    float* big  = st   + (size_t)M_ST * D_;
    float* attn = big  + (size_t)M_ST * 3 * D_;
    float* img  = attn + (size_t)M_ST * D_;
    float* kimg = img  + (size_t)M_IMG * D_;
    float* vimg = kimg + (size_t)M_IMG * D_;

    // --- one-time precompute ---
    gemm_bias<<<dim3(M_IMG/64, 4), 256, 0, stream>>>(
        feat, img_proj_w, img_proj_b, img, M_IMG, 256, 512);
    // cross K/V projections are block-invariant: do them once
    gemm_bias<<<dim3(M_IMG/64, 4), 256, 0, stream>>>(
        img, cross_in_w + 256 * 256, cross_in_b + 256, kimg, M_IMG, 256, 256);
    gemm_bias<<<dim3(M_IMG/64, 4), 256, 0, stream>>>(
        img, cross_in_w + 512 * 256, cross_in_b + 512, vimg, M_IMG, 256, 256);
    init_st<<<M_ST * D_ / 256, 256, 0, stream>>>(st, init_part_tokens, part_id_emb);

    // --- 6 transformer blocks ---
    for (int i = 0; i < 6; ++i) {
        // local MHA
        gemm_bias<<<dim3(M_ST/64, 12), 256, 0, stream>>>(
            st, local_in_w, local_in_b, big, M_ST, 768, 256);
        local_attn<<<512 * 8, 256, 0, stream>>>(big, attn);
        gemm_bias<<<dim3(M_ST/64, 4), 256, 0, stream>>>(
            attn, local_out_w, local_out_b, big, M_ST, 256, 256);
        ln_residual<<<M_ST, 256, 0, stream>>>(st, big, norm1_w + i*256, norm1_b + i*256);

        // cross MHA (K/V precomputed)
        gemm_bias<<<dim3(M_ST/64, 4), 256, 0, stream>>>(
            st, cross_in_w, cross_in_b, big, M_ST, 256, 256);
        cross_attn<<<64 * 8 * 8, 256, 0, stream>>>(big, kimg, vimg, attn);
        gemm_bias<<<dim3(M_ST/64, 4), 256, 0, stream>>>(
            attn, cross_out_w, cross_out_b, big, M_ST, 256, 256);
        ln_residual<<<M_ST, 256, 0, stream>>>(st, big, norm2_w + i*256, norm2_b + i*256);
    }

    // --- coords head ---
    gemm_bias<<<dim3(M_ST/64, 1), 256, 0, stream>>>(
        st, coord_w, coord_b, out, M_ST, 3, 256);
}

// Round 2
// 1905.920 us; speedup vs baseline: 2.3036x; 2.3036x over previous
//
#include <hip/hip_runtime.h>
#include <hip/hip_bf16.h>

// PointCraft++: 6 transformer blocks (local MHA within 64-token parts +
// cross MHA to 49 image tokens) over a (64, 512, 256) state stream.
// Round 2: all GEMMs -> bf16 MFMA (16x16x32), weights pre-converted to bf16,
// A converted fp32->bf16 during reg-staging. Attention/LN remain fp32.

#define B_     64
#define P_     8
#define T_     64
#define S_     512          // P_*T_
#define D_     256
#define H_     8
#define DH_    32
#define NIMG_  49
#define M_ST   32768        // B_*S_
#define M_IMG  3136         // B_*NIMG_

typedef short bf16x8 __attribute__((ext_vector_type(8)));
typedef float f32x4  __attribute__((ext_vector_type(4)));

__device__ inline uint f2b_pk(float x, float y) {
    // round-to-nearest-even fp32 -> bf16, packed pair
    uint bx = __float_as_uint(x), by = __float_as_uint(y);
    bx = (bx + 0x7FFFu + ((bx >> 16) & 1u)) >> 16;
    by = (by + 0x7FFFu + ((by >> 16) & 1u)) >> 16;
    return bx | (by << 16);
}

// ---------------------------------------------------------------------------
// fp32 -> bf16 weight conversion (one-time per launch, tiny)
// ---------------------------------------------------------------------------
__global__ __launch_bounds__(256) void cvt_bf16x4(
    const float4* __restrict__ in, uint2* __restrict__ out, int n4)
{
    int i = blockIdx.x * 256 + threadIdx.x;
    if (i < n4) {
        float4 v = in[i];
        out[i] = make_uint2(f2b_pk(v.x, v.y), f2b_pk(v.z, v.w));
    }
}

// ---------------------------------------------------------------------------
// MFMA GEMM: C[M,N] = A[M,K](fp32) @ W[N,K](bf16)^T + bias[N](fp32)
// 128x128 tile, BK=32, 256 threads = 4 waves (2x2 of 64x64), 4x4 frags of
// 16x16x32 MFMA. A reg-staged with fp32->bf16 cvt; W via global_load_lds x16.
// N must be a multiple of 128, K a multiple of 32. M guarded (clamp+mask).
// ---------------------------------------------------------------------------
__global__ __launch_bounds__(256) void gemm_bf16(
    const float*  __restrict__ A,
    const ushort* __restrict__ W,
    const float*  __restrict__ bias,
    float*        __restrict__ C,
    int M, int N, int K)
{
    __shared__ ushort As[128 * 32];
    __shared__ ushort Bs[128 * 32];

    const int tid  = threadIdx.x;
    const int lane = tid & 63;
    const int wave = tid >> 6;
    const int wr = wave >> 1, wc = wave & 1;
    const int row0 = blockIdx.x * 128, col0 = blockIdx.y * 128;

    f32x4 acc[4][4] = {};

    // staging coords (per thread): 8 bf16 = 16B per round, 2 rounds
    const int skc = (tid & 3) * 8;          // k offset within tile
    const int sr0 = tid >> 2;               // row for round 0 (0..63)

    const int fr  = lane & 15;              // frag row/col
    const int kc2 = (lane >> 4) * 8;        // frag k offset

    for (int k0 = 0; k0 < K; k0 += 32) {
        #pragma unroll
        for (int i = 0; i < 2; ++i) {
            const int r = sr0 + i * 64;
            const int e = (tid + i * 256) * 8;       // lds elem offset
            // A: fp32 load + cvt + ds_write_b128
            int ra = row0 + r; if (ra >= M) ra = M - 1;
            const float* ga = A + (size_t)ra * K + k0 + skc;
            float4 v0 = *reinterpret_cast<const float4*>(ga);
            float4 v1 = *reinterpret_cast<const float4*>(ga + 4);
            uint4 pk;
            pk.x = f2b_pk(v0.x, v0.y);
            pk.y = f2b_pk(v0.z, v0.w);
            pk.z = f2b_pk(v1.x, v1.y);
            pk.w = f2b_pk(v1.z, v1.w);
            *reinterpret_cast<uint4*>(&As[e]) = pk;
            // W: direct async global->LDS, 16B
            const ushort* gb = W + (size_t)(col0 + r) * K + k0 + skc;
            __builtin_amdgcn_global_load_lds(
                (const __attribute__((address_space(1))) void*)gb,
                (__attribute__((address_space(3))) void*)&Bs[e], 16, 0, 0);
        }
        __syncthreads();

        bf16x8 af[4], bf[4];
        #pragma unroll
        for (int i = 0; i < 4; ++i)
            af[i] = *reinterpret_cast<const bf16x8*>(
                &As[(wr * 64 + i * 16 + fr) * 32 + kc2]);
        #pragma unroll
        for (int j = 0; j < 4; ++j)
            bf[j] = *reinterpret_cast<const bf16x8*>(
                &Bs[(wc * 64 + j * 16 + fr) * 32 + kc2]);
        #pragma unroll
        for (int i = 0; i < 4; ++i)
            #pragma unroll
            for (int j = 0; j < 4; ++j)
                acc[i][j] = __builtin_amdgcn_mfma_f32_16x16x32_bf16(
                    af[i], bf[j], acc[i][j], 0, 0, 0);
        __syncthreads();
    }

    // epilogue: D layout col=lane&15, row=(lane>>4)*4+reg
    const int mq = (lane >> 4) * 4;
    #pragma unroll
    for (int j = 0; j < 4; ++j) {
        const int n = col0 + wc * 64 + j * 16 + fr;
        const float bn = bias[n];
        #pragma unroll
        for (int i = 0; i < 4; ++i) {
            const int mbase = row0 + wr * 64 + i * 16 + mq;
            #pragma unroll
            for (int r = 0; r < 4; ++r) {
                const int m = mbase + r;
                if (m < M) C[(size_t)m * N + n] = acc[i][j][r] + bn;
            }
        }
    }
}

// ---------------------------------------------------------------------------
// st init: st[b, s, d] = init_part_tokens[s, d] + part_id_emb[s>>6, d]
// ---------------------------------------------------------------------------
__global__ __launch_bounds__(256) void init_st(
    float* __restrict__ st, const float* __restrict__ init_tokens,
    const float* __restrict__ pid_emb)
{
    size_t i = (size_t)blockIdx.x * 256 + threadIdx.x;
    int d = i & 255;
    int s = (i >> 8) & 511;
    int p = s >> 6;
    st[i] = init_tokens[s * 256 + d] + pid_emb[p * 256 + d];
}

// ---------------------------------------------------------------------------
// Local attention: one block per (part, head). Sq=Sk=64, dh=32.
// ---------------------------------------------------------------------------
__global__ __launch_bounds__(256) void local_attn(
    const float* __restrict__ qkv, float* __restrict__ out)
{
    const int blk = blockIdx.x;          // 512*8
    const int bp  = blk >> 3, h = blk & 7;
    const int tid = threadIdx.x;

    __shared__ float qs[64][33], ks[64][33], vs[64][33];
    __shared__ float ps[64][65];

    const size_t base = (size_t)bp * 64 * 768;
    for (int idx = tid; idx < 2048; idx += 256) {
        int t = idx >> 5, d = idx & 31;
        size_t r = base + (size_t)t * 768 + h * 32 + d;
        qs[t][d] = qkv[r];
        ks[t][d] = qkv[r + 256];
        vs[t][d] = qkv[r + 512];
    }
    __syncthreads();

    const int row = tid >> 2, sub = tid & 3;

    float sc[16];
    #pragma unroll
    for (int j = 0; j < 16; ++j) {
        int c = sub * 16 + j;
        float acc = 0.f;
        #pragma unroll
        for (int k = 0; k < 32; ++k) acc += qs[row][k] * ks[c][k];
        sc[j] = acc * 0.17677669529663689f;   // 1/sqrt(32)
    }
    float m = sc[0];
    #pragma unroll
    for (int j = 1; j < 16; ++j) m = fmaxf(m, sc[j]);
    m = fmaxf(m, __shfl_xor(m, 1));
    m = fmaxf(m, __shfl_xor(m, 2));
    float sum = 0.f;
    #pragma unroll
    for (int j = 0; j < 16; ++j) { sc[j] = __expf(sc[j] - m); sum += sc[j]; }
    sum += __shfl_xor(sum, 1);
    sum += __shfl_xor(sum, 2);
    float inv = 1.f / sum;
    #pragma unroll
    for (int j = 0; j < 16; ++j) ps[row][sub * 16 + j] = sc[j] * inv;
    __syncthreads();

    float acc[8] = {};
    for (int k = 0; k < 64; ++k) {
        float p = ps[row][k];
        #pragma unroll
        for (int j = 0; j < 8; ++j) acc[j] += p * vs[k][sub * 8 + j];
    }
    size_t obase = ((size_t)bp * 64 + row) * 256 + h * 32 + sub * 8;
    #pragma unroll
    for (int j = 0; j < 8; ++j) out[obase + j] = acc[j];
}

// ---------------------------------------------------------------------------
// Cross attention: one block per (batch, head, q-chunk of 64). Sk=49.
// ---------------------------------------------------------------------------
__global__ __launch_bounds__(256) void cross_attn(
    const float* __restrict__ qp, const float* __restrict__ kimg,
    const float* __restrict__ vimg, float* __restrict__ out)
{
    const int blk = blockIdx.x;          // 64*8*8
    const int b = blk >> 6, h = (blk >> 3) & 7, qc = blk & 7;
    const int tid = threadIdx.x;

    __shared__ float qs[64][33], ks[49][33], vs[49][33];
    __shared__ float ps[64][52];

    const size_t qbase = ((size_t)b * 512 + qc * 64) * 256 + h * 32;
    for (int idx = tid; idx < 2048; idx += 256) {
        int t = idx >> 5, d = idx & 31;
        qs[t][d] = qp[qbase + (size_t)t * 256 + d];
    }
    const size_t ibase = (size_t)b * 49 * 256 + h * 32;
    for (int idx = tid; idx < 1568; idx += 256) {
        int n = idx >> 5, d = idx & 31;
        ks[n][d] = kimg[ibase + (size_t)n * 256 + d];
        vs[n][d] = vimg[ibase + (size_t)n * 256 + d];
    }
    __syncthreads();

    const int row = tid >> 2, sub = tid & 3;

    float sc[13];
    int cnt = 0;
    float m = -1e30f;
    for (int c = sub; c < 49; c += 4) {
        float acc = 0.f;
        #pragma unroll
        for (int k = 0; k < 32; ++k) acc += qs[row][k] * ks[c][k];
        acc *= 0.17677669529663689f;
        sc[cnt++] = acc;
        m = fmaxf(m, acc);
    }
    m = fmaxf(m, __shfl_xor(m, 1));
    m = fmaxf(m, __shfl_xor(m, 2));
    float sum = 0.f;
    cnt = 0;
    for (int c = sub; c < 49; c += 4) {
        float e = __expf(sc[cnt] - m);
        sc[cnt++] = e;
        sum += e;
    }
    sum += __shfl_xor(sum, 1);
    sum += __shfl_xor(sum, 2);
    float inv = 1.f / sum;
    cnt = 0;
    for (int c = sub; c < 49; c += 4) ps[row][c] = sc[cnt++] * inv;
    __syncthreads();

    float acc[8] = {};
    for (int k = 0; k < 49; ++k) {
        float p = ps[row][k];
        #pragma unroll
        for (int j = 0; j < 8; ++j) acc[j] += p * vs[k][sub * 8 + j];
    }
    size_t obase = ((size_t)b * 512 + qc * 64 + row) * 256 + h * 32 + sub * 8;
    #pragma unroll
    for (int j = 0; j < 8; ++j) out[obase + j] = acc[j];
}

// ---------------------------------------------------------------------------
// Fused residual + LayerNorm: st = LN(st + delta) * w + b. One block per row.
// ---------------------------------------------------------------------------
__global__ __launch_bounds__(256) void ln_residual(
    float* __restrict__ st, const float* __restrict__ delta,
    const float* __restrict__ w, const float* __restrict__ b)
{
    const int row = blockIdx.x;
    const int tid = threadIdx.x;
    const size_t idx = (size_t)row * 256 + tid;

    float x = st[idx] + delta[idx];
    float s = x, s2 = x * x;
    #pragma unroll
    for (int o = 32; o; o >>= 1) {
        s  += __shfl_down(s, o);
        s2 += __shfl_down(s2, o);
    }
    __shared__ float red[8];
    int wave = tid >> 6, lane = tid & 63;
    if (lane == 0) { red[wave] = s; red[4 + wave] = s2; }
    __syncthreads();
    if (tid == 0) {
        float ts  = red[0] + red[1] + red[2] + red[3];
        float ts2 = red[4] + red[5] + red[6] + red[7];
        float mean = ts * (1.f / 256.f);
        float var  = ts2 * (1.f / 256.f) - mean * mean;
        red[0] = mean;
        red[1] = rsqrtf(var + 1e-5f);
    }
    __syncthreads();
    float mean = red[0], rs = red[1];
    st[idx] = (x - mean) * rs * w[tid] + b[tid];
}

// ---------------------------------------------------------------------------
// Coords head: out[m, n] = st[m,:] . coord_w[n,:] + coord_b[n], n<3.
// 8 rows per block; 32 lanes per row, 8 k each, shuffle-reduce.
// ---------------------------------------------------------------------------
__global__ __launch_bounds__(256) void coord_head(
    const float* __restrict__ st, const float* __restrict__ w,
    const float* __restrict__ b, float* __restrict__ out)
{
    const int row = blockIdx.x * 8 + (threadIdx.x >> 5);
    const int l   = threadIdx.x & 31;
    const float* x = st + (size_t)row * 256 + l * 8;
    float4 x0 = *reinterpret_cast<const float4*>(x);
    float4 x1 = *reinterpret_cast<const float4*>(x + 4);
    float acc[3];
    #pragma unroll
    for (int n = 0; n < 3; ++n) {
        const float* wn = w + n * 256 + l * 8;
        float4 w0 = *reinterpret_cast<const float4*>(wn);
        float4 w1 = *reinterpret_cast<const float4*>(wn + 4);
        acc[n] = x0.x*w0.x + x0.y*w0.y + x0.z*w0.z + x0.w*w0.w
               + x1.x*w1.x + x1.y*w1.y + x1.z*w1.z + x1.w*w1.w;
    }
    #pragma unroll
    for (int o = 16; o; o >>= 1)
        #pragma unroll
        for (int n = 0; n < 3; ++n) acc[n] += __shfl_xor(acc[n], o);
    if (l == 0) {
        #pragma unroll
        for (int n = 0; n < 3; ++n) out[(size_t)row * 3 + n] = acc[n] + b[n];
    }
}

// ---------------------------------------------------------------------------
extern "C" void kernel_launch(void* const* d_in, const int* in_sizes, int n_in,
                              void* d_out, int out_size, void* d_ws, size_t ws_size,
                              hipStream_t stream)
{
    const float* feat             = (const float*)d_in[0];
    const float* img_proj_w      = (const float*)d_in[1];
    const float* img_proj_b      = (const float*)d_in[2];
    const float* init_part_tokens = (const float*)d_in[3];
    const float* part_id_emb     = (const float*)d_in[4];
    const float* local_in_w      = (const float*)d_in[5];
    const float* local_in_b      = (const float*)d_in[6];
    const float* local_out_w     = (const float*)d_in[7];
    const float* local_out_b     = (const float*)d_in[8];
    const float* cross_in_w      = (const float*)d_in[9];
    const float* cross_in_b      = (const float*)d_in[10];
    const float* cross_out_w     = (const float*)d_in[11];
    const float* cross_out_b     = (const float*)d_in[12];
    const float* norm1_w         = (const float*)d_in[13];
    const float* norm1_b         = (const float*)d_in[14];
    const float* norm2_w         = (const float*)d_in[15];
    const float* norm2_b         = (const float*)d_in[16];
    const float* coord_w         = (const float*)d_in[17];
    const float* coord_b         = (const float*)d_in[18];
    float* out = (float*)d_out;

    // Workspace layout:
    //   st   : 32768*256 f32      big : 32768*768 f32     attn: 32768*256 f32
    //   img/kimg/vimg: 3*3136*256 f32
    //   bf16 weights: lw_in 768*256 | lw_out 256*256 | cw_in 768*256 |
    //                 cw_out 256*256 | iw 256*512     (1.31 MB)
    float* st   = (float*)d_ws;
    float* big  = st   + (size_t)M_ST * D_;
    float* attn = big  + (size_t)M_ST * 3 * D_;
    float* img  = attn + (size_t)M_ST * D_;
    float* kimg = img  + (size_t)M_IMG * D_;
    float* vimg = kimg + (size_t)M_IMG * D_;
    ushort* lw_in  = (ushort*)(vimg + (size_t)M_IMG * D_);
    ushort* lw_out = lw_in  + 768 * 256;
    ushort* cw_in  = lw_out + 256 * 256;
    ushort* cw_out = cw_in  + 768 * 256;
    ushort* iw     = cw_out + 256 * 256;

    // --- weight conversion (tiny) ---
    cvt_bf16x4<<<(768*256/4 + 255)/256, 256, 0, stream>>>(
        (const float4*)local_in_w,  (uint2*)lw_in,  768*256/4);
    cvt_bf16x4<<<(256*256/4 + 255)/256, 256, 0, stream>>>(
        (const float4*)local_out_w, (uint2*)lw_out, 256*256/4);
    cvt_bf16x4<<<(768*256/4 + 255)/256, 256, 0, stream>>>(
        (const float4*)cross_in_w,  (uint2*)cw_in,  768*256/4);
    cvt_bf16x4<<<(256*256/4 + 255)/256, 256, 0, stream>>>(
        (const float4*)cross_out_w, (uint2*)cw_out, 256*256/4);
    cvt_bf16x4<<<(256*512/4 + 255)/256, 256, 0, stream>>>(
        (const float4*)img_proj_w,  (uint2*)iw,     256*512/4);

    // --- one-time precompute ---
    gemm_bf16<<<dim3((M_IMG+127)/128, 2), 256, 0, stream>>>(
        feat, iw, img_proj_b, img, M_IMG, 256, 512);
    gemm_bf16<<<dim3((M_IMG+127)/128, 2), 256, 0, stream>>>(
        img, cw_in + 256*256, cross_in_b + 256, kimg, M_IMG, 256, 256);
    gemm_bf16<<<dim3((M_IMG+127)/128, 2), 256, 0, stream>>>(
        img, cw_in + 512*256, cross_in_b + 512, vimg, M_IMG, 256, 256);
    init_st<<<M_ST * D_ / 256, 256, 0, stream>>>(st, init_part_tokens, part_id_emb);

    // --- 6 transformer blocks ---
    for (int i = 0; i < 6; ++i) {
        // local MHA
        gemm_bf16<<<dim3(M_ST/128, 6), 256, 0, stream>>>(
            st, lw_in, local_in_b, big, M_ST, 768, 256);
        local_attn<<<512 * 8, 256, 0, stream>>>(big, attn);
        gemm_bf16<<<dim3(M_ST/128, 2), 256, 0, stream>>>(
            attn, lw_out, local_out_b, big, M_ST, 256, 256);
        ln_residual<<<M_ST, 256, 0, stream>>>(st, big, norm1_w + i*256, norm1_b + i*256);

        // cross MHA (K/V precomputed; only q projection needed)
        gemm_bf16<<<dim3(M_ST/128, 2), 256, 0, stream>>>(
            st, cw_in, cross_in_b, big, M_ST, 256, 256);
        cross_attn<<<64 * 8 * 8, 256, 0, stream>>>(big, kimg, vimg, attn);
        gemm_bf16<<<dim3(M_ST/128, 2), 256, 0, stream>>>(
            attn, cw_out, cross_out_b, big, M_ST, 256, 256);
        ln_residual<<<M_ST, 256, 0, stream>>>(st, big, norm2_w + i*256, norm2_b + i*256);
    }

    // --- coords head ---
    coord_head<<<M_ST / 8, 256, 0, stream>>>(st, coord_w, coord_b, out);
}

// Round 3
// 1025.111 us; speedup vs baseline: 4.2829x; 1.8592x over previous
//
#include <hip/hip_runtime.h>
#include <hip/hip_bf16.h>

// PointCraft++: 6 transformer blocks (local MHA within 64-token parts +
// cross MHA to 49 image tokens) over a (64, 512, 256) state stream.
// Round 3: MFMA attention (swapped QK^T, packed P^T LDS writes, V^T staging),
// bf16 activations end-to-end (GEMM A/C bf16, fused LN emits f32+bf16 state).

#define B_     64
#define P_     8
#define T_     64
#define S_     512
#define D_     256
#define H_     8
#define DH_    32
#define NIMG_  49
#define M_ST   32768
#define M_IMG  3136

typedef short bf16x8 __attribute__((ext_vector_type(8)));
typedef float f32x4  __attribute__((ext_vector_type(4)));

__device__ inline uint f2b_pk(float x, float y) {
    uint bx = __float_as_uint(x), by = __float_as_uint(y);
    bx = (bx + 0x7FFFu + ((bx >> 16) & 1u)) >> 16;
    by = (by + 0x7FFFu + ((by >> 16) & 1u)) >> 16;
    return bx | (by << 16);
}
__device__ inline ushort f2b(float x) {
    uint b = __float_as_uint(x);
    return (ushort)((b + 0x7FFFu + ((b >> 16) & 1u)) >> 16);
}
__device__ inline float b2f(uint lo16) {   // lo16 in bits [15:0]
    return __uint_as_float(lo16 << 16);
}

// ---------------------------------------------------------------------------
// fp32 -> bf16 conversion (weights + feat, one-time per launch)
// ---------------------------------------------------------------------------
__global__ __launch_bounds__(256) void cvt_bf16x4(
    const float4* __restrict__ in, uint2* __restrict__ out, int n4)
{
    int i = blockIdx.x * 256 + threadIdx.x;
    if (i < n4) {
        float4 v = in[i];
        out[i] = make_uint2(f2b_pk(v.x, v.y), f2b_pk(v.z, v.w));
    }
}

// ---------------------------------------------------------------------------
// MFMA GEMM: C[M,N](bf16) = A[M,K](bf16) @ W[N,K](bf16)^T + bias[N](f32)
// 128x128 tile, BK=32, 4 waves (2x2 of 64x64), 16x16x32 MFMA.
// N % 128 == 0, K % 32 == 0. M guarded.
// ---------------------------------------------------------------------------
__global__ __launch_bounds__(256) void gemm_bf16(
    const ushort* __restrict__ A,
    const ushort* __restrict__ W,
    const float*  __restrict__ bias,
    ushort*       __restrict__ C,
    int M, int N, int K)
{
    __shared__ ushort As[128 * 32];
    __shared__ ushort Bs[128 * 32];

    const int tid  = threadIdx.x;
    const int lane = tid & 63;
    const int wave = tid >> 6;
    const int wr = wave >> 1, wc = wave & 1;
    const int row0 = blockIdx.x * 128, col0 = blockIdx.y * 128;

    f32x4 acc[4][4] = {};

    const int skc = (tid & 3) * 8;
    const int sr0 = tid >> 2;
    const int fr  = lane & 15;
    const int kc2 = (lane >> 4) * 8;

    for (int k0 = 0; k0 < K; k0 += 32) {
        #pragma unroll
        for (int i = 0; i < 2; ++i) {
            const int r = sr0 + i * 64;
            const int e = (tid + i * 256) * 8;
            int ra = row0 + r; if (ra >= M) ra = M - 1;
            __builtin_amdgcn_global_load_lds(
                (const __attribute__((address_space(1))) void*)(A + (size_t)ra * K + k0 + skc),
                (__attribute__((address_space(3))) void*)&As[e], 16, 0, 0);
            __builtin_amdgcn_global_load_lds(
                (const __attribute__((address_space(1))) void*)(W + (size_t)(col0 + r) * K + k0 + skc),
                (__attribute__((address_space(3))) void*)&Bs[e], 16, 0, 0);
        }
        __syncthreads();

        bf16x8 af[4], bf[4];
        #pragma unroll
        for (int i = 0; i < 4; ++i)
            af[i] = *reinterpret_cast<const bf16x8*>(&As[(wr * 64 + i * 16 + fr) * 32 + kc2]);
        #pragma unroll
        for (int j = 0; j < 4; ++j)
            bf[j] = *reinterpret_cast<const bf16x8*>(&Bs[(wc * 64 + j * 16 + fr) * 32 + kc2]);
        #pragma unroll
        for (int i = 0; i < 4; ++i)
            #pragma unroll
            for (int j = 0; j < 4; ++j)
                acc[i][j] = __builtin_amdgcn_mfma_f32_16x16x32_bf16(
                    af[i], bf[j], acc[i][j], 0, 0, 0);
        __syncthreads();
    }

    const int mq = (lane >> 4) * 4;
    #pragma unroll
    for (int j = 0; j < 4; ++j) {
        const int n = col0 + wc * 64 + j * 16 + fr;
        const float bn = bias[n];
        #pragma unroll
        for (int i = 0; i < 4; ++i) {
            const int mbase = row0 + wr * 64 + i * 16 + mq;
            #pragma unroll
            for (int r = 0; r < 4; ++r) {
                const int m = mbase + r;
                if (m < M) C[(size_t)m * N + n] = f2b(acc[i][j][r] + bn);
            }
        }
    }
}

// ---------------------------------------------------------------------------
// Fused MFMA attention (local & cross). Grid 512, 256 threads = 4 waves,
// wave w handles heads {w, w+4}. 64 queries/block, 64 keys (cross: 49+mask).
// Swapped QK^T: S^T = mfma(K, Q) so softmax is per-lane + xor16/32, and
// P^T writes to LDS pack as b64. V staged transposed (Vt[d][k']) so PV is
// mfma(P, Vt) with packed b128 reads on both operands.
// ---------------------------------------------------------------------------
template<int CROSS>
__global__ __launch_bounds__(256) void attn_mfma(
    const ushort* __restrict__ qsrc,
    const ushort* __restrict__ ksrc,
    const ushort* __restrict__ vsrc,
    ushort* __restrict__ out)
{
    constexpr int QSTR = CROSS ? 256 : 768;
    constexpr int KSTR = CROSS ? 256 : 768;

    const int bid = blockIdx.x;
    int qrow0, krow0;
    if (CROSS) { qrow0 = (bid >> 3) * 512 + (bid & 7) * 64; krow0 = (bid >> 3) * 49; }
    else       { qrow0 = bid * 64; krow0 = bid * 64; }

    __shared__ ushort P_lds[4][64][72];
    __shared__ ushort Vt_lds[4][32][72];

    const int tid = threadIdx.x;
    const int w = tid >> 6, l = tid & 63;
    const int fr = l & 15, g = l >> 4;
    ushort (*P)[72]  = P_lds[w];
    ushort (*Vt)[72] = Vt_lds[w];

    for (int hh = 0; hh < 2; ++hh) {
        const int h = w + hh * 4;
        const int hoff = h * 32;

        // --- K (A-op) and Q (B-op) fragments straight from global ---
        bf16x8 kf[4], qf[4];
        #pragma unroll
        for (int i = 0; i < 4; ++i) {
            int t = 16 * i + fr;
            if (CROSS && t > 48) t = 48;
            kf[i] = *reinterpret_cast<const bf16x8*>(
                ksrc + (size_t)(krow0 + t) * KSTR + hoff + g * 8);
        }
        #pragma unroll
        for (int j = 0; j < 4; ++j)
            qf[j] = *reinterpret_cast<const bf16x8*>(
                qsrc + (size_t)(qrow0 + 16 * j + fr) * QSTR + hoff + g * 8);

        // --- stage V transposed: Vt[d][k'], pair-packed b32 writes ---
        #pragma unroll
        for (int t2 = 0; t2 < 2; ++t2) {
            const int task = t2 * 64 + l;
            const int rp = task >> 2, cg = task & 3;
            int r0 = 2 * rp, r1 = r0 + 1;
            if (CROSS) { if (r0 > 48) r0 = 48; if (r1 > 48) r1 = 48; }
            const uint4 a = *reinterpret_cast<const uint4*>(
                vsrc + (size_t)(krow0 + r0) * KSTR + hoff + cg * 8);
            const uint4 b = *reinterpret_cast<const uint4*>(
                vsrc + (size_t)(krow0 + r1) * KSTR + hoff + cg * 8);
            const uint ac[4] = {a.x, a.y, a.z, a.w};
            const uint bc[4] = {b.x, b.y, b.z, b.w};
            #pragma unroll
            for (int k = 0; k < 4; ++k) {
                uint lo = (ac[k] & 0xFFFFu)    | (bc[k] << 16);          // elem 2k
                uint hi = (ac[k] >> 16)        | (bc[k] & 0xFFFF0000u);  // elem 2k+1
                *reinterpret_cast<uint*>(&Vt[cg * 8 + 2 * k][2 * rp])     = lo;
                *reinterpret_cast<uint*>(&Vt[cg * 8 + 2 * k + 1][2 * rp]) = hi;
            }
        }

        // --- S^T = K @ Q^T : rows k' = 16i+4g+r, cols q = 16j+fr ---
        f32x4 st_[4][4];
        #pragma unroll
        for (int i = 0; i < 4; ++i)
            #pragma unroll
            for (int j = 0; j < 4; ++j) {
                f32x4 z = {};
                st_[i][j] = __builtin_amdgcn_mfma_f32_16x16x32_bf16(
                    kf[i], qf[j], z, 0, 0, 0);
                st_[i][j] *= 0.17677669529663689f;
            }
        if (CROSS) {
            // k' = 48 + 4g + r >= 49 -> mask
            #pragma unroll
            for (int j = 0; j < 4; ++j)
                #pragma unroll
                for (int r = 0; r < 4; ++r)
                    if (r > 0 || g > 0) st_[3][j][r] = -1e30f;
        }

        // --- softmax over k' (per q-column), normalize, pack P^T to LDS ---
        #pragma unroll
        for (int j = 0; j < 4; ++j) {
            float mx = -1e30f;
            #pragma unroll
            for (int i = 0; i < 4; ++i)
                #pragma unroll
                for (int r = 0; r < 4; ++r) mx = fmaxf(mx, st_[i][j][r]);
            mx = fmaxf(mx, __shfl_xor(mx, 16));
            mx = fmaxf(mx, __shfl_xor(mx, 32));
            float sm = 0.f;
            #pragma unroll
            for (int i = 0; i < 4; ++i)
                #pragma unroll
                for (int r = 0; r < 4; ++r) {
                    float p = __expf(st_[i][j][r] - mx);
                    st_[i][j][r] = p;
                    sm += p;
                }
            sm += __shfl_xor(sm, 16);
            sm += __shfl_xor(sm, 32);
            const float inv = 1.f / sm;
            const int q = 16 * j + fr;
            #pragma unroll
            for (int i = 0; i < 4; ++i) {
                uint lo = f2b_pk(st_[i][j][0] * inv, st_[i][j][1] * inv);
                uint hi = f2b_pk(st_[i][j][2] * inv, st_[i][j][3] * inv);
                *reinterpret_cast<uint2*>(&P[q][16 * i + 4 * g]) = make_uint2(lo, hi);
            }
        }

        __syncthreads();   // P/Vt writes -> cross-lane reads

        // --- O = P @ V : A = P[q][k'], B = Vt[d][k'] ---
        f32x4 o[4][2] = {};
        #pragma unroll
        for (int s = 0; s < 2; ++s) {
            bf16x8 pa[4], vb[2];
            #pragma unroll
            for (int i = 0; i < 4; ++i)
                pa[i] = *reinterpret_cast<const bf16x8*>(&P[16 * i + fr][32 * s + 8 * g]);
            #pragma unroll
            for (int j2 = 0; j2 < 2; ++j2)
                vb[j2] = *reinterpret_cast<const bf16x8*>(&Vt[16 * j2 + fr][32 * s + 8 * g]);
            #pragma unroll
            for (int i = 0; i < 4; ++i)
                #pragma unroll
                for (int j2 = 0; j2 < 2; ++j2)
                    o[i][j2] = __builtin_amdgcn_mfma_f32_16x16x32_bf16(
                        pa[i], vb[j2], o[i][j2], 0, 0, 0);
        }

        // --- store: rows q = 16i+4g+r, col d = 16j2+fr ---
        #pragma unroll
        for (int i = 0; i < 4; ++i)
            #pragma unroll
            for (int j2 = 0; j2 < 2; ++j2)
                #pragma unroll
                for (int r = 0; r < 4; ++r) {
                    const int row = qrow0 + 16 * i + 4 * g + r;
                    out[(size_t)row * 256 + hoff + 16 * j2 + fr] = f2b(o[i][j2][r]);
                }

        __syncthreads();   // protect Vt/P overwrite by next head
    }
}

// ---------------------------------------------------------------------------
// st init: st[b,s,d] = init_part_tokens[s,d] + part_id_emb[s>>6,d] (f32+bf16)
// ---------------------------------------------------------------------------
__global__ __launch_bounds__(256) void init_st(
    float* __restrict__ st, ushort* __restrict__ stb,
    const float* __restrict__ init_tokens, const float* __restrict__ pid_emb)
{
    int i = blockIdx.x * 256 + threadIdx.x;       // over 2,097,152 float4s
    int c = i & 63;
    int s = (i >> 6) & 511;
    int p = s >> 6;
    float4 v = *reinterpret_cast<const float4*>(&init_tokens[s * 256 + c * 4]);
    float4 e = *reinterpret_cast<const float4*>(&pid_emb[p * 256 + c * 4]);
    v.x += e.x; v.y += e.y; v.z += e.z; v.w += e.w;
    *reinterpret_cast<float4*>(&st[(size_t)i * 4]) = v;
    *reinterpret_cast<uint2*>(&stb[(size_t)i * 4]) =
        make_uint2(f2b_pk(v.x, v.y), f2b_pk(v.z, v.w));
}

// ---------------------------------------------------------------------------
// Fused residual + LN: st(f32) = LN(st + delta(bf16)); also emit st bf16.
// 4 rows/block, one wave per row, float4 per lane, shuffle-only reduce.
// ---------------------------------------------------------------------------
__global__ __launch_bounds__(256) void ln_fused(
    float* __restrict__ st, const ushort* __restrict__ delta,
    ushort* __restrict__ stb,
    const float* __restrict__ w, const float* __restrict__ b)
{
    const int row = blockIdx.x * 4 + (threadIdx.x >> 6);
    const int l = threadIdx.x & 63;
    const size_t base = (size_t)row * 256 + l * 4;

    float4 x = *reinterpret_cast<float4*>(&st[base]);
    uint2 dv = *reinterpret_cast<const uint2*>(&delta[base]);
    x.x += b2f(dv.x & 0xFFFFu);
    x.y += __uint_as_float(dv.x & 0xFFFF0000u);
    x.z += b2f(dv.y & 0xFFFFu);
    x.w += __uint_as_float(dv.y & 0xFFFF0000u);

    float s  = x.x + x.y + x.z + x.w;
    float s2 = x.x * x.x + x.y * x.y + x.z * x.z + x.w * x.w;
    #pragma unroll
    for (int o = 32; o; o >>= 1) { s += __shfl_xor(s, o); s2 += __shfl_xor(s2, o); }
    const float mean = s * (1.f / 256.f);
    const float var  = s2 * (1.f / 256.f) - mean * mean;
    const float rs   = rsqrtf(var + 1e-5f);

    const float4 wv = *reinterpret_cast<const float4*>(&w[l * 4]);
    const float4 bv = *reinterpret_cast<const float4*>(&b[l * 4]);
    float4 y;
    y.x = (x.x - mean) * rs * wv.x + bv.x;
    y.y = (x.y - mean) * rs * wv.y + bv.y;
    y.z = (x.z - mean) * rs * wv.z + bv.z;
    y.w = (x.w - mean) * rs * wv.w + bv.w;
    *reinterpret_cast<float4*>(&st[base]) = y;
    *reinterpret_cast<uint2*>(&stb[base]) =
        make_uint2(f2b_pk(y.x, y.y), f2b_pk(y.z, y.w));
}

// ---------------------------------------------------------------------------
// Coords head: out[m,n] = st[m,:] . coord_w[n,:] + coord_b[n], n<3 (f32)
// ---------------------------------------------------------------------------
__global__ __launch_bounds__(256) void coord_head(
    const float* __restrict__ st, const float* __restrict__ w,
    const float* __restrict__ b, float* __restrict__ out)
{
    const int row = blockIdx.x * 8 + (threadIdx.x >> 5);
    const int l   = threadIdx.x & 31;
    const float* x = st + (size_t)row * 256 + l * 8;
    float4 x0 = *reinterpret_cast<const float4*>(x);
    float4 x1 = *reinterpret_cast<const float4*>(x + 4);
    float acc[3];
    #pragma unroll
    for (int n = 0; n < 3; ++n) {
        const float* wn = w + n * 256 + l * 8;
        float4 w0 = *reinterpret_cast<const float4*>(wn);
        float4 w1 = *reinterpret_cast<const float4*>(wn + 4);
        acc[n] = x0.x*w0.x + x0.y*w0.y + x0.z*w0.z + x0.w*w0.w
               + x1.x*w1.x + x1.y*w1.y + x1.z*w1.z + x1.w*w1.w;
    }
    #pragma unroll
    for (int o = 16; o; o >>= 1)
        #pragma unroll
        for (int n = 0; n < 3; ++n) acc[n] += __shfl_xor(acc[n], o);
    if (l == 0) {
        #pragma unroll
        for (int n = 0; n < 3; ++n) out[(size_t)row * 3 + n] = acc[n] + b[n];
    }
}

// ---------------------------------------------------------------------------
extern "C" void kernel_launch(void* const* d_in, const int* in_sizes, int n_in,
                              void* d_out, int out_size, void* d_ws, size_t ws_size,
                              hipStream_t stream)
{
    const float* feat             = (const float*)d_in[0];
    const float* img_proj_w      = (const float*)d_in[1];
    const float* img_proj_b      = (const float*)d_in[2];
    const float* init_part_tokens = (const float*)d_in[3];
    const float* part_id_emb     = (const float*)d_in[4];
    const float* local_in_w      = (const float*)d_in[5];
    const float* local_in_b      = (const float*)d_in[6];
    const float* local_out_w     = (const float*)d_in[7];
    const float* local_out_b     = (const float*)d_in[8];
    const float* cross_in_w      = (const float*)d_in[9];
    const float* cross_in_b      = (const float*)d_in[10];
    const float* cross_out_w     = (const float*)d_in[11];
    const float* cross_out_b     = (const float*)d_in[12];
    const float* norm1_w         = (const float*)d_in[13];
    const float* norm1_b         = (const float*)d_in[14];
    const float* norm2_w         = (const float*)d_in[15];
    const float* norm2_b         = (const float*)d_in[16];
    const float* coord_w         = (const float*)d_in[17];
    const float* coord_b         = (const float*)d_in[18];
    float* out = (float*)d_out;

    // Workspace layout
    float*  st   = (float*)d_ws;                       // 32768*256 f32
    ushort* stb  = (ushort*)(st + (size_t)M_ST * D_);  // 32768*256 bf16
    ushort* big  = stb  + (size_t)M_ST * D_;           // 32768*768 bf16
    ushort* attn = big  + (size_t)M_ST * 3 * D_;       // 32768*256 bf16
    ushort* fbf  = attn + (size_t)M_ST * D_;           // 3136*512
    ushort* img  = fbf  + (size_t)M_IMG * 512;         // 3136*256
    ushort* kimg = img  + (size_t)M_IMG * D_;
    ushort* vimg = kimg + (size_t)M_IMG * D_;
    ushort* lw_in  = vimg  + (size_t)M_IMG * D_;
    ushort* lw_out = lw_in  + 768 * 256;
    ushort* cw_in  = lw_out + 256 * 256;
    ushort* cw_out = cw_in  + 768 * 256;
    ushort* iw     = cw_out + 256 * 256;

    // --- conversions (tiny) ---
    cvt_bf16x4<<<768*256/4/256, 256, 0, stream>>>((const float4*)local_in_w,  (uint2*)lw_in,  768*256/4);
    cvt_bf16x4<<<256*256/4/256, 256, 0, stream>>>((const float4*)local_out_w, (uint2*)lw_out, 256*256/4);
    cvt_bf16x4<<<768*256/4/256, 256, 0, stream>>>((const float4*)cross_in_w,  (uint2*)cw_in,  768*256/4);
    cvt_bf16x4<<<256*256/4/256, 256, 0, stream>>>((const float4*)cross_out_w, (uint2*)cw_out, 256*256/4);
    cvt_bf16x4<<<256*512/4/256, 256, 0, stream>>>((const float4*)img_proj_w,  (uint2*)iw,     256*512/4);
    cvt_bf16x4<<<(M_IMG*512/4 + 255)/256, 256, 0, stream>>>((const float4*)feat, (uint2*)fbf, M_IMG*512/4);

    // --- one-time precompute ---
    gemm_bf16<<<dim3((M_IMG+127)/128, 2), 256, 0, stream>>>(fbf, iw, img_proj_b, img, M_IMG, 256, 512);
    gemm_bf16<<<dim3((M_IMG+127)/128, 2), 256, 0, stream>>>(img, cw_in + 256*256, cross_in_b + 256, kimg, M_IMG, 256, 256);
    gemm_bf16<<<dim3((M_IMG+127)/128, 2), 256, 0, stream>>>(img, cw_in + 512*256, cross_in_b + 512, vimg, M_IMG, 256, 256);
    init_st<<<M_ST * D_ / 4 / 256, 256, 0, stream>>>(st, stb, init_part_tokens, part_id_emb);

    // --- 6 transformer blocks ---
    for (int i = 0; i < 6; ++i) {
        // local MHA
        gemm_bf16<<<dim3(M_ST/128, 6), 256, 0, stream>>>(stb, lw_in, local_in_b, big, M_ST, 768, 256);
        attn_mfma<0><<<512, 256, 0, stream>>>(big, big + 256, big + 512, attn);
        gemm_bf16<<<dim3(M_ST/128, 2), 256, 0, stream>>>(attn, lw_out, local_out_b, big, M_ST, 256, 256);
        ln_fused<<<M_ST/4, 256, 0, stream>>>(st, big, stb, norm1_w + i*256, norm1_b + i*256);

        // cross MHA (K/V precomputed)
        gemm_bf16<<<dim3(M_ST/128, 2), 256, 0, stream>>>(stb, cw_in, cross_in_b, big, M_ST, 256, 256);
        attn_mfma<1><<<512, 256, 0, stream>>>(big, kimg, vimg, attn);
        gemm_bf16<<<dim3(M_ST/128, 2), 256, 0, stream>>>(attn, cw_out, cross_out_b, big, M_ST, 256, 256);
        ln_fused<<<M_ST/4, 256, 0, stream>>>(st, big, stb, norm2_w + i*256, norm2_b + i*256);
    }

    // --- coords head ---
    coord_head<<<M_ST / 8, 256, 0, stream>>>(st, coord_w, coord_b, out);
}

// Round 6
// 916.712 us; speedup vs baseline: 4.7894x; 1.1182x over previous
//
#include <hip/hip_runtime.h>
#include <hip/hip_bf16.h>

// PointCraft++: 6 transformer blocks (local MHA within 64-token parts +
// cross MHA to 49 image tokens) over a (64, 512, 256) state stream.
// Round 6: fix round-4/5 NaN — gemm_bf16 staging must be TWO rounds
// (128x32 tile = 8KB, 256 thr x 16B = 4KB/round); rounds 4/5 staged only
// rows 0..63, leaving rows 64..127 of As/Bs uninitialized.

#define B_     64
#define P_     8
#define T_     64
#define S_     512
#define D_     256
#define H_     8
#define DH_    32
#define NIMG_  49
#define M_ST   32768
#define M_IMG  3136

#define AS1 __attribute__((address_space(1)))
#define AS3 __attribute__((address_space(3)))

typedef short bf16x8 __attribute__((ext_vector_type(8)));
typedef float f32x4  __attribute__((ext_vector_type(4)));

__device__ inline uint f2b_pk(float x, float y) {
    uint bx = __float_as_uint(x), by = __float_as_uint(y);
    bx = (bx + 0x7FFFu + ((bx >> 16) & 1u)) >> 16;
    by = (by + 0x7FFFu + ((by >> 16) & 1u)) >> 16;
    return bx | (by << 16);
}
__device__ inline ushort f2b(float x) {
    uint b = __float_as_uint(x);
    return (ushort)((b + 0x7FFFu + ((b >> 16) & 1u)) >> 16);
}

// ---------------------------------------------------------------------------
// fp32 -> bf16 conversion (weights + feat, one-time per launch)
// ---------------------------------------------------------------------------
__global__ __launch_bounds__(256) void cvt_bf16x4(
    const float4* __restrict__ in, uint2* __restrict__ out, int n4)
{
    int i = blockIdx.x * 256 + threadIdx.x;
    if (i < n4) {
        float4 v = in[i];
        out[i] = make_uint2(f2b_pk(v.x, v.y), f2b_pk(v.z, v.w));
    }
}

// ---------------------------------------------------------------------------
// MFMA GEMM: C[M,N](bf16) = A[M,K](bf16) @ W[N,K](bf16)^T + bias[N](f32)
// 128x128 tile, BK=32, 4 waves (2x2), 16x16x32 MFMA. Coalesced epilogue via
// LDS re-staging (Cs overlays As|Bs). 32 KiB LDS. N%128==0, K%32==0.
// Staging: TWO rounds of 16B per thread per matrix (8KB tile / 4KB round).
// ---------------------------------------------------------------------------
__global__ __launch_bounds__(256) void gemm_bf16(
    const ushort* __restrict__ A,
    const ushort* __restrict__ W,
    const float*  __restrict__ bias,
    ushort*       __restrict__ C,
    int M, int N, int K)
{
    __shared__ ushort smem[128 * 128];   // As: [0,4096) Bs: [4096,8192); Cs: all
    ushort* Asm = smem;
    ushort* Bsm = smem + 4096;

    const int tid  = threadIdx.x;
    const int lane = tid & 63;
    const int wave = tid >> 6;
    const int wr = wave >> 1, wc = wave & 1;
    const int row0 = blockIdx.x * 128, col0 = blockIdx.y * 128;

    f32x4 acc[4][4] = {};

    const int skc = (tid & 3) * 8;
    const int sr0 = tid >> 2;            // 0..63
    const int fr  = lane & 15;
    const int g   = lane >> 4;

    for (int k0 = 0; k0 < K; k0 += 32) {
        #pragma unroll
        for (int i = 0; i < 2; ++i) {
            const int r = sr0 + i * 64;              // 0..127
            const int e = (tid + i * 256) * 8;       // LDS elem 0..4095
            int ra = row0 + r; if (ra >= M) ra = M - 1;
            __builtin_amdgcn_global_load_lds(
                (const AS1 void*)(A + (size_t)ra * K + k0 + skc),
                (AS3 void*)&Asm[e], 16, 0, 0);
            __builtin_amdgcn_global_load_lds(
                (const AS1 void*)(W + (size_t)(col0 + r) * K + k0 + skc),
                (AS3 void*)&Bsm[e], 16, 0, 0);
        }
        __syncthreads();

        bf16x8 af[4], bf[4];
        #pragma unroll
        for (int i = 0; i < 4; ++i)
            af[i] = *reinterpret_cast<const bf16x8*>(&Asm[(wr * 64 + i * 16 + fr) * 32 + g * 8]);
        #pragma unroll
        for (int j = 0; j < 4; ++j)
            bf[j] = *reinterpret_cast<const bf16x8*>(&Bsm[(wc * 64 + j * 16 + fr) * 32 + g * 8]);
        #pragma unroll
        for (int i = 0; i < 4; ++i)
            #pragma unroll
            for (int j = 0; j < 4; ++j)
                acc[i][j] = __builtin_amdgcn_mfma_f32_16x16x32_bf16(
                    af[i], bf[j], acc[i][j], 0, 0, 0);
        __syncthreads();
    }

    // epilogue: bias + pack into Cs (128x128 tile), then coalesced store
    float bn[4];
    #pragma unroll
    for (int j = 0; j < 4; ++j) bn[j] = bias[col0 + wc * 64 + j * 16 + fr];

    #pragma unroll
    for (int i = 0; i < 4; ++i)
        #pragma unroll
        for (int j = 0; j < 4; ++j)
            #pragma unroll
            for (int r = 0; r < 4; ++r)
                smem[(wr * 64 + i * 16 + g * 4 + r) * 128 + wc * 64 + j * 16 + fr] =
                    f2b(acc[i][j][r] + bn[j]);
    __syncthreads();

    #pragma unroll
    for (int it = 0; it < 8; ++it) {
        const int elem = (it * 256 + tid) * 8;
        const int lrow = elem >> 7, lcol = elem & 127;
        const int m = row0 + lrow;
        if (m < M)
            *reinterpret_cast<uint4*>(&C[(size_t)m * N + col0 + lcol]) =
                *reinterpret_cast<const uint4*>(&smem[elem]);
    }
}

// ---------------------------------------------------------------------------
// Fused out-proj GEMM + residual + LayerNorm:
//   x = A @ W^T + bias + st;  st = (x-mean)*rsqrt(var+eps)*lnw + lnb (f32+bf16)
// BM=64, BN=256, BK=32, 256 threads = 4 waves (1x4). Grid = M/64 = 512.
// LDS: As 4K + Bs 16K + Cs 32K + red 2K = 55.3 KiB.
// ---------------------------------------------------------------------------
__global__ __launch_bounds__(256) void gemm_ln(
    const ushort* __restrict__ A,
    const ushort* __restrict__ W,
    const float*  __restrict__ bias,
    float*        __restrict__ st,
    ushort*       __restrict__ stb,
    const float*  __restrict__ lnw,
    const float*  __restrict__ lnb)
{
    __shared__ ushort As[64 * 32];
    __shared__ ushort Bs[256 * 32];
    __shared__ ushort Cs[64 * 256];
    __shared__ float  redS[64][4];
    __shared__ float  redS2[64][4];

    const int tid  = threadIdx.x;
    const int lane = tid & 63;
    const int wc   = tid >> 6;           // wave = N-quarter
    const int fr = lane & 15, g = lane >> 4;
    const int row0 = blockIdx.x * 64;

    f32x4 acc[4][4] = {};
    const int skc = (tid & 3) * 8;
    const int sr  = tid >> 2;            // 0..63

    for (int k0 = 0; k0 < 256; k0 += 32) {
        __builtin_amdgcn_global_load_lds(
            (const AS1 void*)(A + (size_t)(row0 + sr) * 256 + k0 + skc),
            (AS3 void*)&As[tid * 8], 16, 0, 0);
        #pragma unroll
        for (int q = 0; q < 4; ++q)
            __builtin_amdgcn_global_load_lds(
                (const AS1 void*)(W + (size_t)(sr + q * 64) * 256 + k0 + skc),
                (AS3 void*)&Bs[(tid + q * 256) * 8], 16, 0, 0);
        __syncthreads();

        bf16x8 af[4], bf[4];
        #pragma unroll
        for (int i = 0; i < 4; ++i)
            af[i] = *reinterpret_cast<const bf16x8*>(&As[(i * 16 + fr) * 32 + g * 8]);
        #pragma unroll
        for (int j = 0; j < 4; ++j)
            bf[j] = *reinterpret_cast<const bf16x8*>(&Bs[(wc * 64 + j * 16 + fr) * 32 + g * 8]);
        #pragma unroll
        for (int i = 0; i < 4; ++i)
            #pragma unroll
            for (int j = 0; j < 4; ++j)
                acc[i][j] = __builtin_amdgcn_mfma_f32_16x16x32_bf16(
                    af[i], bf[j], acc[i][j], 0, 0, 0);
        __syncthreads();
    }

    // per-lane column params
    int   col[4]; float bv[4], wv[4], lb[4];
    #pragma unroll
    for (int j = 0; j < 4; ++j) {
        col[j] = wc * 64 + j * 16 + fr;
        bv[j]  = bias[col[j]];
        wv[j]  = lnw[col[j]];
        lb[j]  = lnb[col[j]];
    }

    // pass 1: x = acc + bias + st; per-row partial sums -> LDS
    #pragma unroll
    for (int i = 0; i < 4; ++i)
        #pragma unroll
        for (int r = 0; r < 4; ++r) {
            const int rl = i * 16 + g * 4 + r;
            const size_t rb = (size_t)(row0 + rl) * 256;
            float s = 0.f, s2 = 0.f;
            #pragma unroll
            for (int j = 0; j < 4; ++j) {
                float x = acc[i][j][r] + bv[j] + st[rb + col[j]];
                acc[i][j][r] = x;
                s += x; s2 += x * x;
            }
            #pragma unroll
            for (int o = 1; o < 16; o <<= 1) {
                s  += __shfl_xor(s, o);
                s2 += __shfl_xor(s2, o);
            }
            if (fr == 0) { redS[rl][wc] = s; redS2[rl][wc] = s2; }
        }
    __syncthreads();

    // pass 2: normalize, write st (f32) + stage stb tile in Cs
    #pragma unroll
    for (int i = 0; i < 4; ++i)
        #pragma unroll
        for (int r = 0; r < 4; ++r) {
            const int rl = i * 16 + g * 4 + r;
            const size_t rb = (size_t)(row0 + rl) * 256;
            const float ts  = redS[rl][0] + redS[rl][1] + redS[rl][2] + redS[rl][3];
            const float ts2 = redS2[rl][0] + redS2[rl][1] + redS2[rl][2] + redS2[rl][3];
            const float mean = ts * (1.f / 256.f);
            const float var  = ts2 * (1.f / 256.f) - mean * mean;
            const float rs   = rsqrtf(var + 1e-5f);
            #pragma unroll
            for (int j = 0; j < 4; ++j) {
                const float y = (acc[i][j][r] - mean) * rs * wv[j] + lb[j];
                st[rb + col[j]] = y;
                Cs[rl * 256 + col[j]] = f2b(y);
            }
        }
    __syncthreads();

    // coalesced stb store (64 x 256)
    #pragma unroll
    for (int it = 0; it < 8; ++it) {
        const int elem = (it * 256 + tid) * 8;
        const int rl = elem >> 8, c = elem & 255;
        *reinterpret_cast<uint4*>(&stb[(size_t)(row0 + rl) * 256 + c]) =
            *reinterpret_cast<const uint4*>(&Cs[elem]);
    }
}

// ---------------------------------------------------------------------------
// Fused MFMA attention (local & cross). Grid 512, 4 waves, wave w handles
// heads {w, w+4}. Swapped QK^T; V^T staging; coalesced out via Os gather
// (Os OVERLAYS P_lds: P is dead after the PV MFMAs; barrier guards it).
// LDS: P 36K + Vt 18K = 55.3 KiB.
// ---------------------------------------------------------------------------
template<int CROSS>
__global__ __launch_bounds__(256) void attn_mfma(
    const ushort* __restrict__ qsrc,
    const ushort* __restrict__ ksrc,
    const ushort* __restrict__ vsrc,
    ushort* __restrict__ out)
{
    constexpr int QSTR = CROSS ? 256 : 768;
    constexpr int KSTR = CROSS ? 256 : 768;

    const int bid = blockIdx.x;
    int qrow0, krow0;
    if (CROSS) { qrow0 = (bid >> 3) * 512 + (bid & 7) * 64; krow0 = (bid >> 3) * 49; }
    else       { qrow0 = bid * 64; krow0 = bid * 64; }

    __shared__ ushort P_lds[4][64][72];
    __shared__ ushort Vt_lds[4][32][72];
    ushort* Os = &P_lds[0][0][0];        // overlay: 64*128 = 8192 ushorts

    const int tid = threadIdx.x;
    const int w = tid >> 6, l = tid & 63;
    const int fr = l & 15, g = l >> 4;
    ushort (*P)[72]  = P_lds[w];
    ushort (*Vt)[72] = Vt_lds[w];

    for (int hh = 0; hh < 2; ++hh) {
        const int h = w + hh * 4;
        const int hoff = h * 32;

        bf16x8 kf[4], qf[4];
        #pragma unroll
        for (int i = 0; i < 4; ++i) {
            int t = 16 * i + fr;
            if (CROSS && t > 48) t = 48;
            kf[i] = *reinterpret_cast<const bf16x8*>(
                ksrc + (size_t)(krow0 + t) * KSTR + hoff + g * 8);
        }
        #pragma unroll
        for (int j = 0; j < 4; ++j)
            qf[j] = *reinterpret_cast<const bf16x8*>(
                qsrc + (size_t)(qrow0 + 16 * j + fr) * QSTR + hoff + g * 8);

        // stage V transposed: Vt[d][k'], pair-packed b32 writes
        #pragma unroll
        for (int t2 = 0; t2 < 2; ++t2) {
            const int task = t2 * 64 + l;
            const int rp = task >> 2, cg = task & 3;
            int r0 = 2 * rp, r1 = r0 + 1;
            if (CROSS) { if (r0 > 48) r0 = 48; if (r1 > 48) r1 = 48; }
            const uint4 a = *reinterpret_cast<const uint4*>(
                vsrc + (size_t)(krow0 + r0) * KSTR + hoff + cg * 8);
            const uint4 b = *reinterpret_cast<const uint4*>(
                vsrc + (size_t)(krow0 + r1) * KSTR + hoff + cg * 8);
            const uint ac[4] = {a.x, a.y, a.z, a.w};
            const uint bc[4] = {b.x, b.y, b.z, b.w};
            #pragma unroll
            for (int k = 0; k < 4; ++k) {
                uint lo = (ac[k] & 0xFFFFu) | (bc[k] << 16);
                uint hi = (ac[k] >> 16)     | (bc[k] & 0xFFFF0000u);
                *reinterpret_cast<uint*>(&Vt[cg * 8 + 2 * k][2 * rp])     = lo;
                *reinterpret_cast<uint*>(&Vt[cg * 8 + 2 * k + 1][2 * rp]) = hi;
            }
        }

        // S^T = K @ Q^T
        f32x4 st_[4][4];
        #pragma unroll
        for (int i = 0; i < 4; ++i)
            #pragma unroll
            for (int j = 0; j < 4; ++j) {
                f32x4 z = {};
                st_[i][j] = __builtin_amdgcn_mfma_f32_16x16x32_bf16(
                    kf[i], qf[j], z, 0, 0, 0);
                st_[i][j] *= 0.17677669529663689f;
            }
        if (CROSS) {
            #pragma unroll
            for (int j = 0; j < 4; ++j)
                #pragma unroll
                for (int r = 0; r < 4; ++r)
                    if (r > 0 || g > 0) st_[3][j][r] = -1e30f;
        }

        // softmax per q-column, pack P^T
        #pragma unroll
        for (int j = 0; j < 4; ++j) {
            float mx = -1e30f;
            #pragma unroll
            for (int i = 0; i < 4; ++i)
                #pragma unroll
                for (int r = 0; r < 4; ++r) mx = fmaxf(mx, st_[i][j][r]);
            mx = fmaxf(mx, __shfl_xor(mx, 16));
            mx = fmaxf(mx, __shfl_xor(mx, 32));
            float sm = 0.f;
            #pragma unroll
            for (int i = 0; i < 4; ++i)
                #pragma unroll
                for (int r = 0; r < 4; ++r) {
                    float p = __expf(st_[i][j][r] - mx);
                    st_[i][j][r] = p;
                    sm += p;
                }
            sm += __shfl_xor(sm, 16);
            sm += __shfl_xor(sm, 32);
            const float inv = 1.f / sm;
            const int q = 16 * j + fr;
            #pragma unroll
            for (int i = 0; i < 4; ++i) {
                uint lo = f2b_pk(st_[i][j][0] * inv, st_[i][j][1] * inv);
                uint hi = f2b_pk(st_[i][j][2] * inv, st_[i][j][3] * inv);
                *reinterpret_cast<uint2*>(&P[q][16 * i + 4 * g]) = make_uint2(lo, hi);
            }
        }

        __syncthreads();   // P/Vt visible

        // O = P @ V
        f32x4 o[4][2] = {};
        #pragma unroll
        for (int s = 0; s < 2; ++s) {
            bf16x8 pa[4], vb[2];
            #pragma unroll
            for (int i = 0; i < 4; ++i)
                pa[i] = *reinterpret_cast<const bf16x8*>(&P[16 * i + fr][32 * s + 8 * g]);
            #pragma unroll
            for (int j2 = 0; j2 < 2; ++j2)
                vb[j2] = *reinterpret_cast<const bf16x8*>(&Vt[16 * j2 + fr][32 * s + 8 * g]);
            #pragma unroll
            for (int i = 0; i < 4; ++i)
                #pragma unroll
                for (int j2 = 0; j2 < 2; ++j2)
                    o[i][j2] = __builtin_amdgcn_mfma_f32_16x16x32_bf16(
                        pa[i], vb[j2], o[i][j2], 0, 0, 0);
        }

        __syncthreads();   // ALL waves done reading P -> safe to overlay Os

        // gather heads {hh*4 .. hh*4+3} = contiguous 128 cols into Os
        #pragma unroll
        for (int i = 0; i < 4; ++i)
            #pragma unroll
            for (int j2 = 0; j2 < 2; ++j2)
                #pragma unroll
                for (int r = 0; r < 4; ++r)
                    Os[(16 * i + 4 * g + r) * 128 + w * 32 + 16 * j2 + fr] =
                        f2b(o[i][j2][r]);
        __syncthreads();   // Os complete

        // coalesced out store: 64 rows x 128 cols
        #pragma unroll
        for (int it = 0; it < 4; ++it) {
            const int elem = (it * 256 + tid) * 8;
            const int lrow = elem >> 7, lcol = elem & 127;
            *reinterpret_cast<uint4*>(
                &out[(size_t)(qrow0 + lrow) * 256 + hh * 128 + lcol]) =
                *reinterpret_cast<const uint4*>(&Os[elem]);
        }
        __syncthreads();   // Os reads done -> safe for next hh's P/Vt writes
    }
}

// ---------------------------------------------------------------------------
// st init: st[b,s,d] = init_part_tokens[s,d] + part_id_emb[s>>6,d] (f32+bf16)
// ---------------------------------------------------------------------------
__global__ __launch_bounds__(256) void init_st(
    float* __restrict__ st, ushort* __restrict__ stb,
    const float* __restrict__ init_tokens, const float* __restrict__ pid_emb)
{
    int i = blockIdx.x * 256 + threadIdx.x;
    int c = i & 63;
    int s = (i >> 6) & 511;
    int p = s >> 6;
    float4 v = *reinterpret_cast<const float4*>(&init_tokens[s * 256 + c * 4]);
    float4 e = *reinterpret_cast<const float4*>(&pid_emb[p * 256 + c * 4]);
    v.x += e.x; v.y += e.y; v.z += e.z; v.w += e.w;
    *reinterpret_cast<float4*>(&st[(size_t)i * 4]) = v;
    *reinterpret_cast<uint2*>(&stb[(size_t)i * 4]) =
        make_uint2(f2b_pk(v.x, v.y), f2b_pk(v.z, v.w));
}

// ---------------------------------------------------------------------------
// Coords head: out[m,n] = st[m,:] . coord_w[n,:] + coord_b[n], n<3 (f32)
// ---------------------------------------------------------------------------
__global__ __launch_bounds__(256) void coord_head(
    const float* __restrict__ st, const float* __restrict__ w,
    const float* __restrict__ b, float* __restrict__ out)
{
    const int row = blockIdx.x * 8 + (threadIdx.x >> 5);
    const int l   = threadIdx.x & 31;
    const float* x = st + (size_t)row * 256 + l * 8;
    float4 x0 = *reinterpret_cast<const float4*>(x);
    float4 x1 = *reinterpret_cast<const float4*>(x + 4);
    float acc[3];
    #pragma unroll
    for (int n = 0; n < 3; ++n) {
        const float* wn = w + n * 256 + l * 8;
        float4 w0 = *reinterpret_cast<const float4*>(wn);
        float4 w1 = *reinterpret_cast<const float4*>(wn + 4);
        acc[n] = x0.x*w0.x + x0.y*w0.y + x0.z*w0.z + x0.w*w0.w
               + x1.x*w1.x + x1.y*w1.y + x1.z*w1.z + x1.w*w1.w;
    }
    #pragma unroll
    for (int o = 16; o; o >>= 1)
        #pragma unroll
        for (int n = 0; n < 3; ++n) acc[n] += __shfl_xor(acc[n], o);
    if (l == 0) {
        #pragma unroll
        for (int n = 0; n < 3; ++n) out[(size_t)row * 3 + n] = acc[n] + b[n];
    }
}

// ---------------------------------------------------------------------------
extern "C" void kernel_launch(void* const* d_in, const int* in_sizes, int n_in,
                              void* d_out, int out_size, void* d_ws, size_t ws_size,
                              hipStream_t stream)
{
    const float* feat             = (const float*)d_in[0];
    const float* img_proj_w      = (const float*)d_in[1];
    const float* img_proj_b      = (const float*)d_in[2];
    const float* init_part_tokens = (const float*)d_in[3];
    const float* part_id_emb     = (const float*)d_in[4];
    const float* local_in_w      = (const float*)d_in[5];
    const float* local_in_b      = (const float*)d_in[6];
    const float* local_out_w     = (const float*)d_in[7];
    const float* local_out_b     = (const float*)d_in[8];
    const float* cross_in_w      = (const float*)d_in[9];
    const float* cross_in_b      = (const float*)d_in[10];
    const float* cross_out_w     = (const float*)d_in[11];
    const float* cross_out_b     = (const float*)d_in[12];
    const float* norm1_w         = (const float*)d_in[13];
    const float* norm1_b         = (const float*)d_in[14];
    const float* norm2_w         = (const float*)d_in[15];
    const float* norm2_b         = (const float*)d_in[16];
    const float* coord_w         = (const float*)d_in[17];
    const float* coord_b         = (const float*)d_in[18];
    float* out = (float*)d_out;

    // Workspace layout
    float*  st   = (float*)d_ws;                       // 32768*256 f32
    ushort* stb  = (ushort*)(st + (size_t)M_ST * D_);  // 32768*256 bf16
    ushort* big  = stb  + (size_t)M_ST * D_;           // 32768*768 bf16
    ushort* attn = big  + (size_t)M_ST * 3 * D_;       // 32768*256 bf16
    ushort* fbf  = attn + (size_t)M_ST * D_;           // 3136*512
    ushort* img  = fbf  + (size_t)M_IMG * 512;         // 3136*256
    ushort* kimg = img  + (size_t)M_IMG * D_;
    ushort* vimg = kimg + (size_t)M_IMG * D_;
    ushort* lw_in  = vimg  + (size_t)M_IMG * D_;
    ushort* lw_out = lw_in  + 768 * 256;
    ushort* cw_in  = lw_out + 256 * 256;
    ushort* cw_out = cw_in  + 768 * 256;
    ushort* iw     = cw_out + 256 * 256;

    // --- conversions (tiny) ---
    cvt_bf16x4<<<768*256/4/256, 256, 0, stream>>>((const float4*)local_in_w,  (uint2*)lw_in,  768*256/4);
    cvt_bf16x4<<<256*256/4/256, 256, 0, stream>>>((const float4*)local_out_w, (uint2*)lw_out, 256*256/4);
    cvt_bf16x4<<<768*256/4/256, 256, 0, stream>>>((const float4*)cross_in_w,  (uint2*)cw_in,  768*256/4);
    cvt_bf16x4<<<256*256/4/256, 256, 0, stream>>>((const float4*)cross_out_w, (uint2*)cw_out, 256*256/4);
    cvt_bf16x4<<<256*512/4/256, 256, 0, stream>>>((const float4*)img_proj_w,  (uint2*)iw,     256*512/4);
    cvt_bf16x4<<<(M_IMG*512/4 + 255)/256, 256, 0, stream>>>((const float4*)feat, (uint2*)fbf, M_IMG*512/4);

    // --- one-time precompute ---
    gemm_bf16<<<dim3((M_IMG+127)/128, 2), 256, 0, stream>>>(fbf, iw, img_proj_b, img, M_IMG, 256, 512);
    gemm_bf16<<<dim3((M_IMG+127)/128, 2), 256, 0, stream>>>(img, cw_in + 256*256, cross_in_b + 256, kimg, M_IMG, 256, 256);
    gemm_bf16<<<dim3((M_IMG+127)/128, 2), 256, 0, stream>>>(img, cw_in + 512*256, cross_in_b + 512, vimg, M_IMG, 256, 256);
    init_st<<<M_ST * D_ / 4 / 256, 256, 0, stream>>>(st, stb, init_part_tokens, part_id_emb);

    // --- 6 transformer blocks ---
    for (int i = 0; i < 6; ++i) {
        // local MHA
        gemm_bf16<<<dim3(M_ST/128, 6), 256, 0, stream>>>(stb, lw_in, local_in_b, big, M_ST, 768, 256);
        attn_mfma<0><<<512, 256, 0, stream>>>(big, big + 256, big + 512, attn);
        gemm_ln<<<M_ST/64, 256, 0, stream>>>(attn, lw_out, local_out_b, st, stb,
                                             norm1_w + i*256, norm1_b + i*256);
        // cross MHA (K/V precomputed)
        gemm_bf16<<<dim3(M_ST/128, 2), 256, 0, stream>>>(stb, cw_in, cross_in_b, big, M_ST, 256, 256);
        attn_mfma<1><<<512, 256, 0, stream>>>(big, kimg, vimg, attn);
        gemm_ln<<<M_ST/64, 256, 0, stream>>>(attn, cw_out, cross_out_b, st, stb,
                                             norm2_w + i*256, norm2_b + i*256);
    }

    // --- coords head ---
    coord_head<<<M_ST / 8, 256, 0, stream>>>(st, coord_w, coord_b, out);
}